// Round 10
// baseline (117.796 us; speedup 1.0000x reference)
//
#include <hip/hip_runtime.h>

#define N_NODES 20000
#define N_EDGES 640000
#define N_GRAPHS 64

// pool tiling: GSPLIT=4 (16 graphs per block) halves x L2 re-reads vs GSPLIT=8
#define NCHUNK 128
#define CHUNK_SZ 157   // 128*157 = 20096 >= 20000
#define GSPLIT 4
#define GSUB 16

// graph-bucket sort (r3-proven geometry)
#define BG_TILE 2048
#define NBG 313        // ceil(640000/2048)
#define SEGCAP 80
#define GR_CAP 768
#define NSLOT4 (NBG * SEGCAP / 4)   // 6260 uint4 per graph

// ws layout (4B units), ws_size = 256 MiB:
//   Cdcol  [64][20000] f32     at 0
//   deg    [20000] f32         at 1,280,000
//   counts [64] f32            at 1,300,000
//   Y      [64][256] f32       at 1,300,064  (zeroed by bucket tail block)
//   part   [128][64][256] f32  at 1,316,448
//   bh     [313][64] u32       at 3,413,600
//   vals   [64][313][80] u32   at 3,433,632  (ends 5,036,192)
//   glo    [65] u32            at 5,036,192  graph node-range bounds
#define CD_OFF      0
#define DEG_OFF     1280000
#define CNT_OFF     1300000
#define Y_OFF       1300064
#define PART_OFF    1316448
#define BH_OFF      3413600
#define VALS_OFF    3433632
#define GLO_OFF     5036192

// bucket edges by g = batch[src] (r7 verbatim). Tail block does the 65
// graph-range binary searches in parallel + Y zero, off the critical path.
__global__ __launch_bounds__(512) void bucket_g_k(const int* __restrict__ ei,
                                                  const int* __restrict__ batch,
                                                  unsigned* __restrict__ vals,
                                                  unsigned* __restrict__ bh,
                                                  float* __restrict__ Y,
                                                  unsigned* __restrict__ glo) {
    __shared__ unsigned hist[N_GRAPHS];
    __shared__ unsigned base[N_GRAPHS + 1];
    __shared__ unsigned lv[BG_TILE];          // 8 KB reorder tile
    __shared__ unsigned char gidx[BG_TILE];   // 2 KB: output index -> graph
    const int t = threadIdx.x;
    const int blk = blockIdx.x;

    if (blk == NBG) {                          // tail block: glo + Y zero
        if (t < N_GRAPHS + 1) {                // 65 parallel binary searches
            int lo = 0, hi = N_NODES;
            while (lo < hi) { int m = (lo + hi) >> 1; if (batch[m] < t) lo = m + 1; else hi = m; }
            glo[t] = (unsigned)lo;
        }
        float4* y4 = (float4*)Y;
        for (int i = t; i < 64 * 64; i += 512) y4[i] = make_float4(0.f, 0.f, 0.f, 0.f);
        return;
    }

    if (t < N_GRAPHS) hist[t] = 0u;
    __syncthreads();

    const int e0 = blk * BG_TILE;
    const int ecnt = (e0 + BG_TILE <= N_EDGES) ? BG_TILE : (N_EDGES - e0);
    unsigned pv[4], rnk[4], gg[4];
#pragma unroll
    for (int k = 0; k < 4; ++k) {
        int i = t + k * 512;
        if (i < ecnt) {
            unsigned s = (unsigned)ei[e0 + i];
            unsigned d = (unsigned)ei[N_EDGES + e0 + i];
            unsigned g = (unsigned)batch[s];
            pv[k] = (s << 15) | d;
            gg[k] = g;
            rnk[k] = atomicAdd(&hist[g], 1u);
        } else {
            gg[k] = 0xFFFFFFFFu;
        }
    }
    __syncthreads();
    if (t < N_GRAPHS) {                        // wave-0 shfl exclusive scan
        unsigned v = hist[t];
        unsigned sum = v;
#pragma unroll
        for (int off = 1; off < 64; off <<= 1) {
            unsigned u = __shfl_up(sum, off, 64);
            if (t >= off) sum += u;
        }
        base[t + 1] = sum;
        if (t == 0) base[0] = 0u;
        bh[blk * N_GRAPHS + t] = (v > SEGCAP) ? SEGCAP : v;
    }
    __syncthreads();
    if (t < N_GRAPHS) {                        // fill gidx runs
        unsigned b0_ = base[t], b1_ = base[t + 1];
        for (unsigned i = b0_; i < b1_; ++i) gidx[i] = (unsigned char)t;
    }
#pragma unroll
    for (int k = 0; k < 4; ++k) {
        if (gg[k] != 0xFFFFFFFFu) lv[base[gg[k]] + rnk[k]] = pv[k];
    }
    __syncthreads();
    for (int i = t; i < ecnt; i += 512) {      // coalesced per-g runs
        unsigned g = gidx[i];
        unsigned slot = (unsigned)i - base[g];
        if (slot < SEGCAP)
            vals[((size_t)g * NBG + blk) * SEGCAP + slot] = lv[i];
    }
}

// cd (r7 verbatim): 128 blocks = (dst-half, graph), 1024 threads, 20 KB hist.
__global__ __launch_bounds__(1024) void cd_col_k(const unsigned* __restrict__ vals,
                                                 const unsigned* __restrict__ bh,
                                                 const unsigned* __restrict__ glo,
                                                 float* __restrict__ Cdcol,
                                                 float* __restrict__ deg,
                                                 float* __restrict__ counts) {
    __shared__ unsigned scnt[NBG];
    __shared__ unsigned dh[5000];          // 20 KB: 10000 dst bins, u16 halves
    __shared__ unsigned sdeg[GR_CAP];      // 3 KB (h==1 only)
    __shared__ unsigned rc[16];
    const int t = threadIdx.x;
    const int g = blockIdx.x & 63;
    const int h = blockIdx.x >> 6;
    const int dbase = h * 10000;

    for (int i = t; i < 5000; i += 1024) dh[i] = 0u;
    if (h) { if (t < GR_CAP) sdeg[t] = 0u; }
    if (t < NBG) scnt[t] = bh[t * N_GRAPHS + g];
    __syncthreads();
    const int lo = (int)glo[g];
    const int hi = (int)glo[g + 1];

    const uint4* v4 = (const uint4*)(vals + (size_t)g * NBG * SEGCAP);
    for (int i = t; i < NSLOT4; i += 1024) {
        uint4 v = *(v4 + i);
        unsigned w = (unsigned)i * 4u;
        unsigned seg = (unsigned)(((unsigned long long)w * 53687092ull) >> 32);  // w/80 exact
        unsigned local = w - seg * 80u;
        unsigned c = scnt[seg];
#define CD_ONE(VX, L)                                                            \
        if ((L) < c) {                                                           \
            int rd_ = (int)((VX) & 0x7FFFu) - dbase;                             \
            if ((unsigned)rd_ < 10000u)                                          \
                atomicAdd(&dh[rd_ >> 1], 1u << ((rd_ & 1) * 16));                \
            if (h) {                                                             \
                int rs_ = (int)((VX) >> 15) - lo;                                \
                if ((unsigned)rs_ < (unsigned)GR_CAP) atomicAdd(&sdeg[rs_], 1u); \
            }                                                                    \
        }
        CD_ONE(v.x, local + 0u)
        CD_ONE(v.y, local + 1u)
        CD_ONE(v.z, local + 2u)
        CD_ONE(v.w, local + 3u)
#undef CD_ONE
    }
    __syncthreads();

    float2* outc = (float2*)(Cdcol + (size_t)g * N_NODES + dbase);
    for (int w = t; w < 5000; w += 1024) {
        unsigned v = dh[w];
        outc[w] = make_float2((float)(v & 0xFFFFu), (float)(v >> 16));
    }
    if (h) {
        const int range = hi - lo;
        for (int i = t; i < range; i += 1024) deg[lo + i] = (float)sdeg[i];
    } else {
        unsigned s = 0;                        // counts[g]: parallel reduce
        for (int i = t; i < NBG; i += 1024) s += scnt[i];
#pragma unroll
        for (int off = 32; off; off >>= 1) s += __shfl_down(s, off, 64);
        if ((t & 63) == 0) rc[t >> 6] = s;
        __syncthreads();
        if (t == 0) {
            unsigned tot = 0;
#pragma unroll
            for (int i = 0; i < 16; ++i) tot += rc[i];
            counts[g] = (float)tot;
        }
    }
}

// 8 accumulators (ACC+0..ACC+7) updated from c-pair (C0,C1)
#define FMA8X(ACC, C0, C1, XV)                                          \
    acc[ACC+0].x = fmaf(C0.x, XV.x, acc[ACC+0].x); acc[ACC+0].y = fmaf(C0.x, XV.y, acc[ACC+0].y); \
    acc[ACC+0].z = fmaf(C0.x, XV.z, acc[ACC+0].z); acc[ACC+0].w = fmaf(C0.x, XV.w, acc[ACC+0].w); \
    acc[ACC+1].x = fmaf(C0.y, XV.x, acc[ACC+1].x); acc[ACC+1].y = fmaf(C0.y, XV.y, acc[ACC+1].y); \
    acc[ACC+1].z = fmaf(C0.y, XV.z, acc[ACC+1].z); acc[ACC+1].w = fmaf(C0.y, XV.w, acc[ACC+1].w); \
    acc[ACC+2].x = fmaf(C0.z, XV.x, acc[ACC+2].x); acc[ACC+2].y = fmaf(C0.z, XV.y, acc[ACC+2].y); \
    acc[ACC+2].z = fmaf(C0.z, XV.z, acc[ACC+2].z); acc[ACC+2].w = fmaf(C0.z, XV.w, acc[ACC+2].w); \
    acc[ACC+3].x = fmaf(C0.w, XV.x, acc[ACC+3].x); acc[ACC+3].y = fmaf(C0.w, XV.y, acc[ACC+3].y); \
    acc[ACC+3].z = fmaf(C0.w, XV.z, acc[ACC+3].z); acc[ACC+3].w = fmaf(C0.w, XV.w, acc[ACC+3].w); \
    acc[ACC+4].x = fmaf(C1.x, XV.x, acc[ACC+4].x); acc[ACC+4].y = fmaf(C1.x, XV.y, acc[ACC+4].y); \
    acc[ACC+4].z = fmaf(C1.x, XV.z, acc[ACC+4].z); acc[ACC+4].w = fmaf(C1.x, XV.w, acc[ACC+4].w); \
    acc[ACC+5].x = fmaf(C1.y, XV.x, acc[ACC+5].x); acc[ACC+5].y = fmaf(C1.y, XV.y, acc[ACC+5].y); \
    acc[ACC+5].z = fmaf(C1.y, XV.z, acc[ACC+5].z); acc[ACC+5].w = fmaf(C1.y, XV.w, acc[ACC+5].w); \
    acc[ACC+6].x = fmaf(C1.z, XV.x, acc[ACC+6].x); acc[ACC+6].y = fmaf(C1.z, XV.y, acc[ACC+6].y); \
    acc[ACC+6].z = fmaf(C1.z, XV.z, acc[ACC+6].z); acc[ACC+6].w = fmaf(C1.z, XV.w, acc[ACC+6].w); \
    acc[ACC+7].x = fmaf(C1.w, XV.x, acc[ACC+7].x); acc[ACC+7].y = fmaf(C1.w, XV.y, acc[ACC+7].y); \
    acc[ACC+7].z = fmaf(C1.w, XV.z, acc[ACC+7].z); acc[ACC+7].w = fmaf(C1.w, XV.w, acc[ACC+7].w);

#define FMA16(I, XV)                                               \
    { float4 c0_ = sc4[(I) * 4], c1_ = sc4[(I) * 4 + 1];           \
      float4 c2_ = sc4[(I) * 4 + 2], c3_ = sc4[(I) * 4 + 3];       \
      FMA8X(0, c0_, c1_, XV)                                       \
      FMA8X(8, c2_, c3_, XV) }

// pool (r8 structure): block = (chunk b, split j of 4); 16 graphs/block.
// Staging remapped (i = e>>4, k = e&15): per wave-instruction the 64 lanes
// cover 4 nodes x 16 k -> 32 banks at 2 lanes/bank (free) instead of the
// old per-k layout's 2 banks at 32 lanes/bank (32-way conflict). LDS layout
// and values unchanged -> part bit-identical.
__global__ __launch_bounds__(256) void pool_k(const float* __restrict__ x,
                                              const int* __restrict__ batch,
                                              const float* __restrict__ Cdcol,
                                              const float* __restrict__ deg,
                                              float* __restrict__ Y,
                                              float* __restrict__ part) {
    __shared__ float4 sc4[CHUNK_SZ * 4];      // 10 KB: [node][4] float4 (GSUB=16)
    __shared__ float sdeg[CHUNK_SZ];
    __shared__ int   sbatch[CHUNK_SZ];
    __shared__ float4 red[2 * GSUB * 64];     // 32 KB cross-phase reduce

    const int t = threadIdx.x;
    const int fg = t & 63;                    // float4 feature group
    const int p  = t >> 6;                    // phase == wave id
    const int b = blockIdx.x & 127;           // same chunk's 4 splits: same XCD mod 8
    const int j = blockIdx.x >> 7;            // 0..3
    const int n0 = b * CHUNK_SZ;
    const int cnt = (n0 + CHUNK_SZ <= N_NODES) ? CHUNK_SZ : (N_NODES - n0);

    // transpose-stage 16 Cd columns into [node][16] LDS layout (conflict-free)
    float* sc = (float*)sc4;
    const float* cbase = Cdcol + (size_t)(j * GSUB) * N_NODES + n0;
    for (int e = t; e < cnt * GSUB; e += 256) {
        int i = e >> 4;
        int k = e & 15;
        sc[e] = cbase[(size_t)k * N_NODES + i];
    }
    if (j == 0) {
        for (int i = t; i < cnt; i += 256) {
            sdeg[i] = deg[n0 + i];
            sbatch[i] = batch[n0 + i];
        }
    }
    __syncthreads();

    const float4* xp = (const float4*)x + (size_t)n0 * 64 + fg;
#define XL(I) xp[(size_t)(I) * 64]
    float4 acc[GSUB];
#pragma unroll
    for (int k = 0; k < GSUB; ++k) acc[k] = make_float4(0.f, 0.f, 0.f, 0.f);

    if (j == 0) {
        // src pooling path (1/4 of blocks): prefetch-1 loop, wave-uniform flushes
        float4 accs = make_float4(0.f, 0.f, 0.f, 0.f);
        int gprev = (p < cnt) ? sbatch[p] : 0;
        int i = p;
        float4 xn = make_float4(0.f, 0.f, 0.f, 0.f);
        if (i < cnt) xn = XL(i);
        for (; i < cnt; i += 4) {
            float4 xv = xn;
            if (i + 4 < cnt) xn = XL(i + 4);
            int g = sbatch[i];                  // wave-uniform
            if (g != gprev) {                   // uniform branch
                float* yr = Y + gprev * 256 + fg * 4;
                atomicAdd(yr + 0, accs.x); atomicAdd(yr + 1, accs.y);
                atomicAdd(yr + 2, accs.z); atomicAdd(yr + 3, accs.w);
                accs = make_float4(0.f, 0.f, 0.f, 0.f);
                gprev = g;
            }
            float dg = sdeg[i];
            accs.x = fmaf(dg, xv.x, accs.x); accs.y = fmaf(dg, xv.y, accs.y);
            accs.z = fmaf(dg, xv.z, accs.z); accs.w = fmaf(dg, xv.w, accs.w);
            FMA16(i, xv)
        }
        if (p < cnt) {
            float* yr = Y + gprev * 256 + fg * 4;
            atomicAdd(yr + 0, accs.x); atomicAdd(yr + 1, accs.y);
            atomicAdd(yr + 2, accs.z); atomicAdd(yr + 3, accs.w);
        }
    } else {
        // dst-only path: unroll x4, 4 loads in flight
        int i = p;
        float4 xa, xb, xc, xd;
        if (i      < cnt) xa = XL(i);
        if (i + 4  < cnt) xb = XL(i + 4);
        if (i + 8  < cnt) xc = XL(i + 8);
        if (i + 12 < cnt) xd = XL(i + 12);
        for (; i + 12 < cnt; i += 16) {
            float4 y0 = xa, y1 = xb, y2 = xc, y3 = xd;
            if (i + 16 < cnt) xa = XL(i + 16);
            if (i + 20 < cnt) xb = XL(i + 20);
            if (i + 24 < cnt) xc = XL(i + 24);
            if (i + 28 < cnt) xd = XL(i + 28);
            FMA16(i, y0)
            FMA16(i + 4, y1)
            FMA16(i + 8, y2)
            FMA16(i + 12, y3)
        }
        for (; i < cnt; i += 4) {
            float4 xv = XL(i);
            FMA16(i, xv)
        }
    }
#undef XL

    // cross-phase reduce 4 -> 2 -> 1 (same tree as r3: (p0+p2)+(p1+p3))
    if (p >= 2) {
#pragma unroll
        for (int k = 0; k < GSUB; ++k) red[(p - 2) * (GSUB * 64) + k * 64 + fg] = acc[k];
    }
    __syncthreads();
    if (p < 2) {
#pragma unroll
        for (int k = 0; k < GSUB; ++k) {
            float4 v = red[p * (GSUB * 64) + k * 64 + fg];
            acc[k].x += v.x; acc[k].y += v.y; acc[k].z += v.z; acc[k].w += v.w;
        }
    }
    __syncthreads();
    if (p == 1) {
#pragma unroll
        for (int k = 0; k < GSUB; ++k) red[k * 64 + fg] = acc[k];
    }
    __syncthreads();
    if (p == 0) {
        float4* part4 = (float4*)part;
#pragma unroll
        for (int k = 0; k < GSUB; ++k) {
            float4 v = red[k * 64 + fg];
            acc[k].x += v.x; acc[k].y += v.y; acc[k].z += v.z; acc[k].w += v.w;
            part4[(size_t)(b * 64 + j * GSUB + k) * 64 + fg] = acc[k];
        }
    }
}

// chain (r9 verbatim): 128 blocks x 512 threads, slab-split + 4-way split-k.
__global__ __launch_bounds__(512) void chain2_k(const float* __restrict__ Y,
                                                const float* __restrict__ part,
                                                const float* __restrict__ counts,
                                                const float* __restrict__ W0, const float* __restrict__ b0,
                                                const float* __restrict__ W1, const float* __restrict__ b1,
                                                const float* __restrict__ W2, const float* __restrict__ b2,
                                                float* __restrict__ out) {
    __shared__ float m[256];
    __shared__ float pp[512];   // split partials (slab halves / k-quarters)
    __shared__ float h[128];
    const int r = blockIdx.x;
    const int t = threadIdx.x;
    const int g = r & 63;
    const int half = (r >= 64) ? 128 : 0;
    const int t256 = t & 255;   // feature for part-reduce
    const int sk = t >> 8;      // slab half 0/1
    const int tt = t & 127;     // layer output feature
    const int ks = t >> 7;      // k-split id 0..3

    float c = counts[g];
    float inv = 1.0f / fmaxf(c, 1.0f);
    float beta = c * inv;

    if (r < 64) {
        if (t < 256) m[t] = Y[g * 256 + t] * inv;
    } else {
        float s = 0.0f;
        const float* pbase = part + ((size_t)(sk * 64) * 64 + g) * 256 + t256;
#pragma unroll 16
        for (int bb = 0; bb < 64; ++bb) s += pbase[(size_t)bb * 64 * 256];
        pp[t] = s;
        __syncthreads();
        if (t < 256) m[t] = (pp[t] + pp[t + 256]) * inv;
    }
    __syncthreads();

    // layer 1: m(256) @ W0(256x128) -> 128, k split 4 x 64
    {
        float s = 0.0f;
        const float* w = W0 + (ks * 64) * 128 + tt;
        const float* mm = m + ks * 64;
#pragma unroll 8
        for (int k = 0; k < 64; ++k) s = fmaf(mm[k], w[k * 128], s);
        pp[t] = s;
    }
    __syncthreads();
    if (t < 128) {
        float s1 = (pp[t] + pp[t + 128]) + (pp[t + 256] + pp[t + 384]) + beta * b0[t];
        out[g * 768 + 0 + half + t] = s1;
        h[t] = s1;
    }
    __syncthreads();

    // layer 2: h(128) @ W1(128x128) -> 128, k split 4 x 32
    {
        float s = 0.0f;
        const float* w = W1 + (ks * 32) * 128 + tt;
        const float* hh = h + ks * 32;
#pragma unroll 8
        for (int k = 0; k < 32; ++k) s = fmaf(hh[k], w[k * 128], s);
        pp[t] = s;
    }
    __syncthreads();
    float s2 = 0.0f;
    if (t < 128) {
        s2 = (pp[t] + pp[t + 128]) + (pp[t + 256] + pp[t + 384]) + beta * b1[t];
        out[g * 768 + 256 + half + t] = s2;
    }
    __syncthreads();
    if (t < 128) h[t] = s2;
    __syncthreads();

    // layer 3: h(128) @ W2(128x128) -> 128, k split 4 x 32
    {
        float s = 0.0f;
        const float* w = W2 + (ks * 32) * 128 + tt;
        const float* hh = h + ks * 32;
#pragma unroll 8
        for (int k = 0; k < 32; ++k) s = fmaf(hh[k], w[k * 128], s);
        pp[t] = s;
    }
    __syncthreads();
    if (t < 128) {
        float s3 = (pp[t] + pp[t + 128]) + (pp[t + 256] + pp[t + 384]) + beta * b2[t];
        out[g * 768 + 512 + half + t] = s3;
    }
}

extern "C" void kernel_launch(void* const* d_in, const int* in_sizes, int n_in,
                              void* d_out, int out_size, void* d_ws, size_t ws_size,
                              hipStream_t stream) {
    const float* x     = (const float*)d_in[0];
    const int*   ei    = (const int*)d_in[1];
    const int*   batch = (const int*)d_in[2];
    const float* W0    = (const float*)d_in[3];
    const float* b0    = (const float*)d_in[4];
    const float* W1    = (const float*)d_in[5];
    const float* b1    = (const float*)d_in[6];
    const float* W2    = (const float*)d_in[7];
    const float* b2    = (const float*)d_in[8];
    float* out = (float*)d_out;

    float*    ws     = (float*)d_ws;
    float*    Cdcol  = ws + CD_OFF;
    float*    deg    = ws + DEG_OFF;
    float*    counts = ws + CNT_OFF;
    float*    Y      = ws + Y_OFF;
    float*    part   = ws + PART_OFF;
    unsigned* bh     = (unsigned*)(ws + BH_OFF);
    unsigned* vals   = (unsigned*)(ws + VALS_OFF);
    unsigned* glo    = (unsigned*)(ws + GLO_OFF);

    bucket_g_k<<<NBG + 1, 512, 0, stream>>>(ei, batch, vals, bh, Y, glo);
    cd_col_k<<<128, 1024, 0, stream>>>(vals, bh, glo, Cdcol, deg, counts);
    pool_k<<<NCHUNK * GSPLIT, 256, 0, stream>>>(x, batch, Cdcol, deg, Y, part);
    chain2_k<<<128, 512, 0, stream>>>(Y, part, counts, W0, b0, W1, b1, W2, b2, out);
}

// Round 11
// 115.886 us; speedup vs baseline: 1.0165x; 1.0165x over previous
//
#include <hip/hip_runtime.h>

#define N_NODES 20000
#define N_EDGES 640000
#define N_GRAPHS 64

// pool tiling: GSPLIT=4 (16 graphs per block) halves x L2 re-reads vs GSPLIT=8
#define NCHUNK 128
#define CHUNK_SZ 157   // 128*157 = 20096 >= 20000
#define GSPLIT 4
#define GSUB 16

// graph-bucket sort (r3-proven geometry)
#define BG_TILE 2048
#define NBG 313        // ceil(640000/2048)
#define SEGCAP 80
#define GR_CAP 768
#define NSLOT4 (NBG * SEGCAP / 4)   // 6260 uint4 per graph

// ws layout (4B units), ws_size = 256 MiB:
//   Cdcol  [64][20000] f32     at 0
//   deg    [20000] f32         at 1,280,000
//   counts [64] f32            at 1,300,000
//   Y      [64][256] f32       at 1,300,064  (zeroed by bucket tail block)
//   part   [128][64][256] f32  at 1,316,448
//   bh     [313][64] u32       at 3,413,600
//   vals   [64][313][80] u32   at 3,433,632  (ends 5,036,192)
//   glo    [65] u32            at 5,036,192  graph node-range bounds
#define CD_OFF      0
#define DEG_OFF     1280000
#define CNT_OFF     1300000
#define Y_OFF       1300064
#define PART_OFF    1316448
#define BH_OFF      3413600
#define VALS_OFF    3433632
#define GLO_OFF     5036192

// bucket edges by g = batch[src] (r7 verbatim). Tail block does the 65
// graph-range binary searches in parallel + Y zero, off the critical path.
__global__ __launch_bounds__(512) void bucket_g_k(const int* __restrict__ ei,
                                                  const int* __restrict__ batch,
                                                  unsigned* __restrict__ vals,
                                                  unsigned* __restrict__ bh,
                                                  float* __restrict__ Y,
                                                  unsigned* __restrict__ glo) {
    __shared__ unsigned hist[N_GRAPHS];
    __shared__ unsigned base[N_GRAPHS + 1];
    __shared__ unsigned lv[BG_TILE];          // 8 KB reorder tile
    __shared__ unsigned char gidx[BG_TILE];   // 2 KB: output index -> graph
    const int t = threadIdx.x;
    const int blk = blockIdx.x;

    if (blk == NBG) {                          // tail block: glo + Y zero
        if (t < N_GRAPHS + 1) {                // 65 parallel binary searches
            int lo = 0, hi = N_NODES;
            while (lo < hi) { int m = (lo + hi) >> 1; if (batch[m] < t) lo = m + 1; else hi = m; }
            glo[t] = (unsigned)lo;
        }
        float4* y4 = (float4*)Y;
        for (int i = t; i < 64 * 64; i += 512) y4[i] = make_float4(0.f, 0.f, 0.f, 0.f);
        return;
    }

    if (t < N_GRAPHS) hist[t] = 0u;
    __syncthreads();

    const int e0 = blk * BG_TILE;
    const int ecnt = (e0 + BG_TILE <= N_EDGES) ? BG_TILE : (N_EDGES - e0);
    unsigned pv[4], rnk[4], gg[4];
#pragma unroll
    for (int k = 0; k < 4; ++k) {
        int i = t + k * 512;
        if (i < ecnt) {
            unsigned s = (unsigned)ei[e0 + i];
            unsigned d = (unsigned)ei[N_EDGES + e0 + i];
            unsigned g = (unsigned)batch[s];
            pv[k] = (s << 15) | d;
            gg[k] = g;
            rnk[k] = atomicAdd(&hist[g], 1u);
        } else {
            gg[k] = 0xFFFFFFFFu;
        }
    }
    __syncthreads();
    if (t < N_GRAPHS) {                        // wave-0 shfl exclusive scan
        unsigned v = hist[t];
        unsigned sum = v;
#pragma unroll
        for (int off = 1; off < 64; off <<= 1) {
            unsigned u = __shfl_up(sum, off, 64);
            if (t >= off) sum += u;
        }
        base[t + 1] = sum;
        if (t == 0) base[0] = 0u;
        bh[blk * N_GRAPHS + t] = (v > SEGCAP) ? SEGCAP : v;
    }
    __syncthreads();
    if (t < N_GRAPHS) {                        // fill gidx runs
        unsigned b0_ = base[t], b1_ = base[t + 1];
        for (unsigned i = b0_; i < b1_; ++i) gidx[i] = (unsigned char)t;
    }
#pragma unroll
    for (int k = 0; k < 4; ++k) {
        if (gg[k] != 0xFFFFFFFFu) lv[base[gg[k]] + rnk[k]] = pv[k];
    }
    __syncthreads();
    for (int i = t; i < ecnt; i += 512) {      // coalesced per-g runs
        unsigned g = gidx[i];
        unsigned slot = (unsigned)i - base[g];
        if (slot < SEGCAP)
            vals[((size_t)g * NBG + blk) * SEGCAP + slot] = lv[i];
    }
}

// cd (r7 verbatim): 128 blocks = (dst-half, graph), 1024 threads, 20 KB hist.
__global__ __launch_bounds__(1024) void cd_col_k(const unsigned* __restrict__ vals,
                                                 const unsigned* __restrict__ bh,
                                                 const unsigned* __restrict__ glo,
                                                 float* __restrict__ Cdcol,
                                                 float* __restrict__ deg,
                                                 float* __restrict__ counts) {
    __shared__ unsigned scnt[NBG];
    __shared__ unsigned dh[5000];          // 20 KB: 10000 dst bins, u16 halves
    __shared__ unsigned sdeg[GR_CAP];      // 3 KB (h==1 only)
    __shared__ unsigned rc[16];
    const int t = threadIdx.x;
    const int g = blockIdx.x & 63;
    const int h = blockIdx.x >> 6;
    const int dbase = h * 10000;

    for (int i = t; i < 5000; i += 1024) dh[i] = 0u;
    if (h) { if (t < GR_CAP) sdeg[t] = 0u; }
    if (t < NBG) scnt[t] = bh[t * N_GRAPHS + g];
    __syncthreads();
    const int lo = (int)glo[g];
    const int hi = (int)glo[g + 1];

    const uint4* v4 = (const uint4*)(vals + (size_t)g * NBG * SEGCAP);
    for (int i = t; i < NSLOT4; i += 1024) {
        uint4 v = *(v4 + i);
        unsigned w = (unsigned)i * 4u;
        unsigned seg = (unsigned)(((unsigned long long)w * 53687092ull) >> 32);  // w/80 exact
        unsigned local = w - seg * 80u;
        unsigned c = scnt[seg];
#define CD_ONE(VX, L)                                                            \
        if ((L) < c) {                                                           \
            int rd_ = (int)((VX) & 0x7FFFu) - dbase;                             \
            if ((unsigned)rd_ < 10000u)                                          \
                atomicAdd(&dh[rd_ >> 1], 1u << ((rd_ & 1) * 16));                \
            if (h) {                                                             \
                int rs_ = (int)((VX) >> 15) - lo;                                \
                if ((unsigned)rs_ < (unsigned)GR_CAP) atomicAdd(&sdeg[rs_], 1u); \
            }                                                                    \
        }
        CD_ONE(v.x, local + 0u)
        CD_ONE(v.y, local + 1u)
        CD_ONE(v.z, local + 2u)
        CD_ONE(v.w, local + 3u)
#undef CD_ONE
    }
    __syncthreads();

    float2* outc = (float2*)(Cdcol + (size_t)g * N_NODES + dbase);
    for (int w = t; w < 5000; w += 1024) {
        unsigned v = dh[w];
        outc[w] = make_float2((float)(v & 0xFFFFu), (float)(v >> 16));
    }
    if (h) {
        const int range = hi - lo;
        for (int i = t; i < range; i += 1024) deg[lo + i] = (float)sdeg[i];
    } else {
        unsigned s = 0;                        // counts[g]: parallel reduce
        for (int i = t; i < NBG; i += 1024) s += scnt[i];
#pragma unroll
        for (int off = 32; off; off >>= 1) s += __shfl_down(s, off, 64);
        if ((t & 63) == 0) rc[t >> 6] = s;
        __syncthreads();
        if (t == 0) {
            unsigned tot = 0;
#pragma unroll
            for (int i = 0; i < 16; ++i) tot += rc[i];
            counts[g] = (float)tot;
        }
    }
}

// 8 accumulators (ACC+0..ACC+7) updated from c-pair (C0,C1)
#define FMA8X(ACC, C0, C1, XV)                                          \
    acc[ACC+0].x = fmaf(C0.x, XV.x, acc[ACC+0].x); acc[ACC+0].y = fmaf(C0.x, XV.y, acc[ACC+0].y); \
    acc[ACC+0].z = fmaf(C0.x, XV.z, acc[ACC+0].z); acc[ACC+0].w = fmaf(C0.x, XV.w, acc[ACC+0].w); \
    acc[ACC+1].x = fmaf(C0.y, XV.x, acc[ACC+1].x); acc[ACC+1].y = fmaf(C0.y, XV.y, acc[ACC+1].y); \
    acc[ACC+1].z = fmaf(C0.y, XV.z, acc[ACC+1].z); acc[ACC+1].w = fmaf(C0.y, XV.w, acc[ACC+1].w); \
    acc[ACC+2].x = fmaf(C0.z, XV.x, acc[ACC+2].x); acc[ACC+2].y = fmaf(C0.z, XV.y, acc[ACC+2].y); \
    acc[ACC+2].z = fmaf(C0.z, XV.z, acc[ACC+2].z); acc[ACC+2].w = fmaf(C0.z, XV.w, acc[ACC+2].w); \
    acc[ACC+3].x = fmaf(C0.w, XV.x, acc[ACC+3].x); acc[ACC+3].y = fmaf(C0.w, XV.y, acc[ACC+3].y); \
    acc[ACC+3].z = fmaf(C0.w, XV.z, acc[ACC+3].z); acc[ACC+3].w = fmaf(C0.w, XV.w, acc[ACC+3].w); \
    acc[ACC+4].x = fmaf(C1.x, XV.x, acc[ACC+4].x); acc[ACC+4].y = fmaf(C1.x, XV.y, acc[ACC+4].y); \
    acc[ACC+4].z = fmaf(C1.x, XV.z, acc[ACC+4].z); acc[ACC+4].w = fmaf(C1.x, XV.w, acc[ACC+4].w); \
    acc[ACC+5].x = fmaf(C1.y, XV.x, acc[ACC+5].x); acc[ACC+5].y = fmaf(C1.y, XV.y, acc[ACC+5].y); \
    acc[ACC+5].z = fmaf(C1.y, XV.z, acc[ACC+5].z); acc[ACC+5].w = fmaf(C1.y, XV.w, acc[ACC+5].w); \
    acc[ACC+6].x = fmaf(C1.z, XV.x, acc[ACC+6].x); acc[ACC+6].y = fmaf(C1.z, XV.y, acc[ACC+6].y); \
    acc[ACC+6].z = fmaf(C1.z, XV.z, acc[ACC+6].z); acc[ACC+6].w = fmaf(C1.z, XV.w, acc[ACC+6].w); \
    acc[ACC+7].x = fmaf(C1.w, XV.x, acc[ACC+7].x); acc[ACC+7].y = fmaf(C1.w, XV.y, acc[ACC+7].y); \
    acc[ACC+7].z = fmaf(C1.w, XV.z, acc[ACC+7].z); acc[ACC+7].w = fmaf(C1.w, XV.w, acc[ACC+7].w);

#define FMA16(I, XV)                                               \
    { float4 c0_ = sc4[(I) * 4], c1_ = sc4[(I) * 4 + 1];           \
      float4 c2_ = sc4[(I) * 4 + 2], c3_ = sc4[(I) * 4 + 3];       \
      FMA8X(0, c0_, c1_, XV)                                       \
      FMA8X(8, c2_, c3_, XV) }

// pool (r9 verbatim — r10's staging remap reverted: coalesced 256B global
// reads per wave beat conflict-free LDS writes; staging is load-bound).
__global__ __launch_bounds__(256) void pool_k(const float* __restrict__ x,
                                              const int* __restrict__ batch,
                                              const float* __restrict__ Cdcol,
                                              const float* __restrict__ deg,
                                              float* __restrict__ Y,
                                              float* __restrict__ part) {
    __shared__ float4 sc4[CHUNK_SZ * 4];      // 10 KB: [node][4] float4 (GSUB=16)
    __shared__ float sdeg[CHUNK_SZ];
    __shared__ int   sbatch[CHUNK_SZ];
    __shared__ float4 red[2 * GSUB * 64];     // 32 KB cross-phase reduce

    const int t = threadIdx.x;
    const int fg = t & 63;                    // float4 feature group
    const int p  = t >> 6;                    // phase == wave id
    const int b = blockIdx.x & 127;           // same chunk's 4 splits: same XCD mod 8
    const int j = blockIdx.x >> 7;            // 0..3
    const int n0 = b * CHUNK_SZ;
    const int cnt = (n0 + CHUNK_SZ <= N_NODES) ? CHUNK_SZ : (N_NODES - n0);

    // transpose-stage 16 Cd columns into [node][16] LDS layout
    float* sc = (float*)sc4;
    const float* cbase = Cdcol + (size_t)(j * GSUB) * N_NODES + n0;
#pragma unroll
    for (int k = 0; k < GSUB; ++k)
        for (int i = t; i < cnt; i += 256)
            sc[i * GSUB + k] = cbase[(size_t)k * N_NODES + i];
    if (j == 0) {
        for (int i = t; i < cnt; i += 256) {
            sdeg[i] = deg[n0 + i];
            sbatch[i] = batch[n0 + i];
        }
    }
    __syncthreads();

    const float4* xp = (const float4*)x + (size_t)n0 * 64 + fg;
#define XL(I) xp[(size_t)(I) * 64]
    float4 acc[GSUB];
#pragma unroll
    for (int k = 0; k < GSUB; ++k) acc[k] = make_float4(0.f, 0.f, 0.f, 0.f);

    if (j == 0) {
        // src pooling path (1/4 of blocks): prefetch-1 loop, wave-uniform flushes
        float4 accs = make_float4(0.f, 0.f, 0.f, 0.f);
        int gprev = (p < cnt) ? sbatch[p] : 0;
        int i = p;
        float4 xn = make_float4(0.f, 0.f, 0.f, 0.f);
        if (i < cnt) xn = XL(i);
        for (; i < cnt; i += 4) {
            float4 xv = xn;
            if (i + 4 < cnt) xn = XL(i + 4);
            int g = sbatch[i];                  // wave-uniform
            if (g != gprev) {                   // uniform branch
                float* yr = Y + gprev * 256 + fg * 4;
                atomicAdd(yr + 0, accs.x); atomicAdd(yr + 1, accs.y);
                atomicAdd(yr + 2, accs.z); atomicAdd(yr + 3, accs.w);
                accs = make_float4(0.f, 0.f, 0.f, 0.f);
                gprev = g;
            }
            float dg = sdeg[i];
            accs.x = fmaf(dg, xv.x, accs.x); accs.y = fmaf(dg, xv.y, accs.y);
            accs.z = fmaf(dg, xv.z, accs.z); accs.w = fmaf(dg, xv.w, accs.w);
            FMA16(i, xv)
        }
        if (p < cnt) {
            float* yr = Y + gprev * 256 + fg * 4;
            atomicAdd(yr + 0, accs.x); atomicAdd(yr + 1, accs.y);
            atomicAdd(yr + 2, accs.z); atomicAdd(yr + 3, accs.w);
        }
    } else {
        // dst-only path: unroll x4, 4 loads in flight
        int i = p;
        float4 xa, xb, xc, xd;
        if (i      < cnt) xa = XL(i);
        if (i + 4  < cnt) xb = XL(i + 4);
        if (i + 8  < cnt) xc = XL(i + 8);
        if (i + 12 < cnt) xd = XL(i + 12);
        for (; i + 12 < cnt; i += 16) {
            float4 y0 = xa, y1 = xb, y2 = xc, y3 = xd;
            if (i + 16 < cnt) xa = XL(i + 16);
            if (i + 20 < cnt) xb = XL(i + 20);
            if (i + 24 < cnt) xc = XL(i + 24);
            if (i + 28 < cnt) xd = XL(i + 28);
            FMA16(i, y0)
            FMA16(i + 4, y1)
            FMA16(i + 8, y2)
            FMA16(i + 12, y3)
        }
        for (; i < cnt; i += 4) {
            float4 xv = XL(i);
            FMA16(i, xv)
        }
    }
#undef XL

    // cross-phase reduce 4 -> 2 -> 1 (same tree as r3: (p0+p2)+(p1+p3))
    if (p >= 2) {
#pragma unroll
        for (int k = 0; k < GSUB; ++k) red[(p - 2) * (GSUB * 64) + k * 64 + fg] = acc[k];
    }
    __syncthreads();
    if (p < 2) {
#pragma unroll
        for (int k = 0; k < GSUB; ++k) {
            float4 v = red[p * (GSUB * 64) + k * 64 + fg];
            acc[k].x += v.x; acc[k].y += v.y; acc[k].z += v.z; acc[k].w += v.w;
        }
    }
    __syncthreads();
    if (p == 1) {
#pragma unroll
        for (int k = 0; k < GSUB; ++k) red[k * 64 + fg] = acc[k];
    }
    __syncthreads();
    if (p == 0) {
        float4* part4 = (float4*)part;
#pragma unroll
        for (int k = 0; k < GSUB; ++k) {
            float4 v = red[k * 64 + fg];
            acc[k].x += v.x; acc[k].y += v.y; acc[k].z += v.z; acc[k].w += v.w;
            part4[(size_t)(b * 64 + j * GSUB + k) * 64 + fg] = acc[k];
        }
    }
}

// chain (r9 verbatim): 128 blocks x 512 threads, slab-split + 4-way split-k.
__global__ __launch_bounds__(512) void chain2_k(const float* __restrict__ Y,
                                                const float* __restrict__ part,
                                                const float* __restrict__ counts,
                                                const float* __restrict__ W0, const float* __restrict__ b0,
                                                const float* __restrict__ W1, const float* __restrict__ b1,
                                                const float* __restrict__ W2, const float* __restrict__ b2,
                                                float* __restrict__ out) {
    __shared__ float m[256];
    __shared__ float pp[512];   // split partials (slab halves / k-quarters)
    __shared__ float h[128];
    const int r = blockIdx.x;
    const int t = threadIdx.x;
    const int g = r & 63;
    const int half = (r >= 64) ? 128 : 0;
    const int t256 = t & 255;   // feature for part-reduce
    const int sk = t >> 8;      // slab half 0/1
    const int tt = t & 127;     // layer output feature
    const int ks = t >> 7;      // k-split id 0..3

    float c = counts[g];
    float inv = 1.0f / fmaxf(c, 1.0f);
    float beta = c * inv;

    if (r < 64) {
        if (t < 256) m[t] = Y[g * 256 + t] * inv;
    } else {
        float s = 0.0f;
        const float* pbase = part + ((size_t)(sk * 64) * 64 + g) * 256 + t256;
#pragma unroll 16
        for (int bb = 0; bb < 64; ++bb) s += pbase[(size_t)bb * 64 * 256];
        pp[t] = s;
        __syncthreads();
        if (t < 256) m[t] = (pp[t] + pp[t + 256]) * inv;
    }
    __syncthreads();

    // layer 1: m(256) @ W0(256x128) -> 128, k split 4 x 64
    {
        float s = 0.0f;
        const float* w = W0 + (ks * 64) * 128 + tt;
        const float* mm = m + ks * 64;
#pragma unroll 8
        for (int k = 0; k < 64; ++k) s = fmaf(mm[k], w[k * 128], s);
        pp[t] = s;
    }
    __syncthreads();
    if (t < 128) {
        float s1 = (pp[t] + pp[t + 128]) + (pp[t + 256] + pp[t + 384]) + beta * b0[t];
        out[g * 768 + 0 + half + t] = s1;
        h[t] = s1;
    }
    __syncthreads();

    // layer 2: h(128) @ W1(128x128) -> 128, k split 4 x 32
    {
        float s = 0.0f;
        const float* w = W1 + (ks * 32) * 128 + tt;
        const float* hh = h + ks * 32;
#pragma unroll 8
        for (int k = 0; k < 32; ++k) s = fmaf(hh[k], w[k * 128], s);
        pp[t] = s;
    }
    __syncthreads();
    float s2 = 0.0f;
    if (t < 128) {
        s2 = (pp[t] + pp[t + 128]) + (pp[t + 256] + pp[t + 384]) + beta * b1[t];
        out[g * 768 + 256 + half + t] = s2;
    }
    __syncthreads();
    if (t < 128) h[t] = s2;
    __syncthreads();

    // layer 3: h(128) @ W2(128x128) -> 128, k split 4 x 32
    {
        float s = 0.0f;
        const float* w = W2 + (ks * 32) * 128 + tt;
        const float* hh = h + ks * 32;
#pragma unroll 8
        for (int k = 0; k < 32; ++k) s = fmaf(hh[k], w[k * 128], s);
        pp[t] = s;
    }
    __syncthreads();
    if (t < 128) {
        float s3 = (pp[t] + pp[t + 128]) + (pp[t + 256] + pp[t + 384]) + beta * b2[t];
        out[g * 768 + 512 + half + t] = s3;
    }
}

extern "C" void kernel_launch(void* const* d_in, const int* in_sizes, int n_in,
                              void* d_out, int out_size, void* d_ws, size_t ws_size,
                              hipStream_t stream) {
    const float* x     = (const float*)d_in[0];
    const int*   ei    = (const int*)d_in[1];
    const int*   batch = (const int*)d_in[2];
    const float* W0    = (const float*)d_in[3];
    const float* b0    = (const float*)d_in[4];
    const float* W1    = (const float*)d_in[5];
    const float* b1    = (const float*)d_in[6];
    const float* W2    = (const float*)d_in[7];
    const float* b2    = (const float*)d_in[8];
    float* out = (float*)d_out;

    float*    ws     = (float*)d_ws;
    float*    Cdcol  = ws + CD_OFF;
    float*    deg    = ws + DEG_OFF;
    float*    counts = ws + CNT_OFF;
    float*    Y      = ws + Y_OFF;
    float*    part   = ws + PART_OFF;
    unsigned* bh     = (unsigned*)(ws + BH_OFF);
    unsigned* vals   = (unsigned*)(ws + VALS_OFF);
    unsigned* glo    = (unsigned*)(ws + GLO_OFF);

    bucket_g_k<<<NBG + 1, 512, 0, stream>>>(ei, batch, vals, bh, Y, glo);
    cd_col_k<<<128, 1024, 0, stream>>>(vals, bh, glo, Cdcol, deg, counts);
    pool_k<<<NCHUNK * GSPLIT, 256, 0, stream>>>(x, batch, Cdcol, deg, Y, part);
    chain2_k<<<128, 512, 0, stream>>>(Y, part, counts, W0, b0, W1, b1, W2, b2, out);
}